// Round 14
// baseline (358.444 us; speedup 1.0000x reference)
//
#include <hip/hip_runtime.h>
#include <math.h>
#include <stdint.h>

// LSTMModel B=1024 T=512 D=32 H=64, 2 layers + fc1(relu) + fc2.
// Round 14: MINIMAL-CONVOY block: 256 blocks x 4 batches, 256 threads =
//   4 waves, 1 wave/SIMD (no intra-SIMD contention), 8 tiles/wave.
//   w0/w1 = L0 (units 0-31 / 32-63), w2/w3 = L1. Row map: tile i, A-row ar
//   -> g = (ar&3)*64 + 32*wl + 4*(ar>>2) + (i&3) + 16*(i>>2), so lane
//   (cq,cj) acc[r] of tile i = gate r of unit 32wl+4cq+(i&3)+16(i>>2).
//   Lane updates 2 units: tiles dsel and dsel+4 (dsel=cj>>2, cb=cj&3).
//   Dup-free h frags + wrap-read (col=l&3); skew pipeline (L1 lags 1);
//   one lgkm-only barrier/step; x direct from global depth-2;
//   log2e folded; bias as MFMA C-init. __launch_bounds__(256,1).

namespace {

constexpr int Hh = 64, Dd = 32, Tt = 512;
constexpr float LOG2E = 1.4426950408889634f;

typedef _Float16 f16x8 __attribute__((ext_vector_type(8)));
typedef float f32x4 __attribute__((ext_vector_type(4)));

__device__ __forceinline__ f32x4 mfma(f16x8 a, f16x8 b, f32x4 c) {
    return __builtin_amdgcn_mfma_f32_16x16x32_f16(a, b, c, 0, 0, 0);
}
__device__ __forceinline__ float rcpf(float x) { return __builtin_amdgcn_rcpf(x); }
__device__ __forceinline__ float exp2f_(float x) { return __builtin_amdgcn_exp2f(x); }
__device__ __forceinline__ float sigm_s(float p) { return rcpf(1.0f + exp2f_(-p)); }
__device__ __forceinline__ float tanh_s(float p) {
    return 1.0f - 2.0f * rcpf(exp2f_(p) + 1.0f);
}
__device__ __forceinline__ float tanh_n(float c) {
    return 1.0f - 2.0f * rcpf(exp2f_(c * (2.0f * LOG2E)) + 1.0f);
}
__device__ __forceinline__ f16x8 cvt8s(const float* p, float sc) {
    f16x8 r;
#pragma unroll
    for (int e = 0; e < 8; ++e) r[e] = (_Float16)(p[e] * sc);
    return r;
}
__device__ __forceinline__ void bar_lgkm() {
    asm volatile("s_waitcnt lgkmcnt(0)\n\ts_barrier" ::: "memory");
}

__global__ __launch_bounds__(256, 1) void lstm_f16(
    const float* __restrict__ x,     // [B, T, D]
    const float* __restrict__ Wih0,  // [256, 32]
    const float* __restrict__ Whh0,  // [256, 64]
    const float* __restrict__ bih0, const float* __restrict__ bhh0,
    const float* __restrict__ Wih1,  // [256, 64]
    const float* __restrict__ Whh1,  // [256, 64]
    const float* __restrict__ bih1, const float* __restrict__ bhh1,
    const float* __restrict__ fc1w,  // [32, 64]
    const float* __restrict__ fc1b,  // [32]
    const float* __restrict__ fc2w,  // [1, 32]
    const float* __restrict__ fc2b,  // [1]
    float* __restrict__ out)         // [B]
{
    // h frag: [parity][kfrag][row = kq*4 + col][e], col = real batch 0..3
    __shared__ __align__(16) _Float16 s_h0[2][2][16][8];  // 1 KB
    __shared__ __align__(16) _Float16 s_h1[2][2][16][8];  // 1 KB
    __shared__ float s_hf[Hh][5];
    __shared__ float s_fcw[32 * 65];
    __shared__ float s_fc[32][5];

    const int tid = threadIdx.x;   // 0..255
    const int w = tid >> 6;        // wave 0..3
    const int l = tid & 63;
    const int ar = l & 15;         // A row within tile
    const int akb = l >> 4;        // k-group
    const int cq = l >> 4;         // C/D row block
    const int cj = l & 15;         // C/D col
    const int cb = cj & 3;         // real batch col
    const int dsel = cj >> 2;      // tile select (0..3); pairs with dsel+4
    const bool isL1w = (w >= 2);   // wave role
    const int wl = w & 1;          // unit half (0: units 0-31, 1: 32-63)
    const int b0 = blockIdx.x * 4;

    // ---- persistent A fragments (log2e folded), 8 tiles per wave ----
    // tile i, A-row ar -> g = (ar&3)*64 + 32wl + 4*(ar>>2) + (i&3) + 16*(i>>2)
    const int r4 = ar & 3;
    const float sc = (r4 == 2) ? 2.0f * LOG2E : LOG2E;
    const int gbase = r4 * 64 + 32 * wl + 4 * (ar >> 2);
    f16x8 Afr[8][4];
    if (!isL1w) {
#pragma unroll
        for (int i = 0; i < 8; ++i) {
            const int g = gbase + (i & 3) + 16 * (i >> 2);
            Afr[i][0] = cvt8s(Wih0 + g * Dd + akb * 8, sc);       // x (K=32)
            Afr[i][1] = cvt8s(Whh0 + g * Hh + akb * 8, sc);       // h0 k0-31
            Afr[i][2] = cvt8s(Whh0 + g * Hh + 32 + akb * 8, sc);  // h0 k32-63
        }
    } else {
#pragma unroll
        for (int i = 0; i < 8; ++i) {
            const int g = gbase + (i & 3) + 16 * (i >> 2);
            Afr[i][0] = cvt8s(Wih1 + g * Hh + akb * 8, sc);       // h0 k0-31
            Afr[i][1] = cvt8s(Wih1 + g * Hh + 32 + akb * 8, sc);  // h0 k32-63
            Afr[i][2] = cvt8s(Whh1 + g * Hh + akb * 8, sc);       // h1 k0-31
            Afr[i][3] = cvt8s(Whh1 + g * Hh + 32 + akb * 8, sc);  // h1 k32-63
        }
    }

    // bias as C-init: biasT[i][r] = gate r of unit 32wl+4cq+(i&3)+16(i>>2)
    const float* bi = isL1w ? bih1 : bih0;
    const float* bhp = isL1w ? bhh1 : bhh0;
    f32x4 biasT[8];
#pragma unroll
    for (int i = 0; i < 8; ++i)
#pragma unroll
        for (int r = 0; r < 4; ++r) {
            const float s2 = (r == 2) ? 2.0f * LOG2E : LOG2E;
            const int uu = 32 * wl + 4 * cq + (i & 3) + 16 * (i >> 2);
            biasT[i][r] = s2 * (bi[r * 64 + uu] + bhp[r * 64 + uu]);
        }

    // lane's 2 update targets: u1 = 32wl+4cq+dsel (tile dsel), u2 = u1+16
    const int u1 = 32 * wl + 4 * cq + dsel;
    const int kf_h = u1 >> 5;                        // same kf for u1,u2
    const int row_h = ((u1 & 31) >> 3) * 4 + cb;
    const int e_h = u1 & 7;
    // u2 slot = u1 slot + 8 rows = +64 f16 elems
    _Float16* const wsel = isL1w ? &s_h1[1][kf_h][row_h][e_h]
                                 : &s_h0[0][kf_h][row_h][e_h];
    const int wdelta = isL1w ? -256 : 256;  // f16 elems per parity flip

    // b-frag read row: wrap col = l&3 (4-lane broadcast)
    const int rrow = (l >> 4) * 4 + (l & 3);

    // x direct-load base: batch b0+cb, k = akb*8..+7
    const float* xbase = x + ((size_t)(b0 + cb) * Tt) * Dd + akb * 8;

    // zero h frag buffers (256 dwords each, 256 threads)
    ((int*)s_h0)[tid] = 0;
    ((int*)s_h1)[tid] = 0;

    float4 xr0, xr1;
    f16x8 xcur;
    if (!isL1w) {
        xr0 = *(const float4*)(xbase);
        xr1 = *(const float4*)(xbase + 4);
#pragma unroll
        for (int e = 0; e < 4; ++e) {
            xcur[e] = (_Float16)xr0[e];
            xcur[4 + e] = (_Float16)xr1[e];
        }
        xr0 = *(const float4*)(xbase + Dd);
        xr1 = *(const float4*)(xbase + Dd + 4);
    }
    float cst1 = 0.f, cst2 = 0.f;
    __syncthreads();

#pragma unroll 2
    for (int t = 0; t < Tt; ++t) {
        const int pr = t & 1;

        f32x4 acc[8];
        if (!isL1w) {
            const f16x8 b0a = *(const f16x8*)&s_h0[pr ^ 1][0][rrow][0];
            const f16x8 b0b = *(const f16x8*)&s_h0[pr ^ 1][1][rrow][0];
#pragma unroll
            for (int i = 0; i < 8; ++i) {
                f32x4 a = mfma(Afr[i][0], xcur, biasT[i]);
                a = mfma(Afr[i][1], b0a, a);
                acc[i] = mfma(Afr[i][2], b0b, a);
            }
            // rotate x prefetch (depth 2)
            f16x8 xn;
#pragma unroll
            for (int e = 0; e < 4; ++e) {
                xn[e] = (_Float16)xr0[e];
                xn[4 + e] = (_Float16)xr1[e];
            }
            const int tf = (t + 2 < Tt) ? (t + 2) : (Tt - 1);
            xr0 = *(const float4*)(xbase + (size_t)tf * Dd);
            xr1 = *(const float4*)(xbase + (size_t)tf * Dd + 4);
            xcur = xn;
        } else {
            const f16x8 b1a = *(const f16x8*)&s_h1[pr][0][rrow][0];      // h1(t-2)
            const f16x8 b1b = *(const f16x8*)&s_h1[pr][1][rrow][0];
            const f16x8 b0a = *(const f16x8*)&s_h0[pr ^ 1][0][rrow][0];  // h0(t-1)
            const f16x8 b0b = *(const f16x8*)&s_h0[pr ^ 1][1][rrow][0];
#pragma unroll
            for (int i = 0; i < 8; ++i) {
                f32x4 a = mfma(Afr[i][0], b0a, biasT[i]);
                a = mfma(Afr[i][1], b0b, a);
                a = mfma(Afr[i][2], b1a, a);
                acc[i] = mfma(Afr[i][3], b1b, a);
            }
        }

        // static 4-way selects (cndmask) for the lane's two tiles
        const f32x4 sA01 = (dsel & 1) ? acc[1] : acc[0];
        const f32x4 sA23 = (dsel & 1) ? acc[3] : acc[2];
        const f32x4 gA = (dsel & 2) ? sA23 : sA01;
        const f32x4 sB01 = (dsel & 1) ? acc[5] : acc[4];
        const f32x4 sB23 = (dsel & 1) ? acc[7] : acc[6];
        const f32x4 gB = (dsel & 2) ? sB23 : sB01;

        // two cell updates (units u1, u2)
        float hv1, hv2;
        {
            const float gi = sigm_s(gA[0]);
            const float gf = sigm_s(gA[1]);
            const float zz = tanh_s(gA[2]);
            const float go = sigm_s(gA[3]);
            float cn = gf * cst1 + gi * zz;
            float hv = go * tanh_n(cn);
            if (t == 0) { cn = isL1w ? 0.f : cn; hv = isL1w ? 0.f : hv; }
            cst1 = cn;
            hv1 = hv;
        }
        {
            const float gi = sigm_s(gB[0]);
            const float gf = sigm_s(gB[1]);
            const float zz = tanh_s(gB[2]);
            const float go = sigm_s(gB[3]);
            float cn = gf * cst2 + gi * zz;
            float hv = go * tanh_n(cn);
            if (t == 0) { cn = isL1w ? 0.f : cn; hv = isL1w ? 0.f : hv; }
            cst2 = cn;
            hv2 = hv;
        }
        _Float16* wp = wsel + (pr ? wdelta : 0);
        wp[0] = (_Float16)hv1;     // unit u1
        wp[64] = (_Float16)hv2;    // unit u1+16 (+8 rows)
        bar_lgkm();
    }

    // ---- epilogue: final L1 step -> h1(511) from h0(511), h1(510) ----
    if (isL1w) {
        const f16x8 b1a = *(const f16x8*)&s_h1[0][0][rrow][0];
        const f16x8 b1b = *(const f16x8*)&s_h1[0][1][rrow][0];
        const f16x8 b0a = *(const f16x8*)&s_h0[1][0][rrow][0];
        const f16x8 b0b = *(const f16x8*)&s_h0[1][1][rrow][0];
        f32x4 acc[8];
#pragma unroll
        for (int i = 0; i < 8; ++i) {
            f32x4 a = mfma(Afr[i][0], b0a, biasT[i]);
            a = mfma(Afr[i][1], b0b, a);
            a = mfma(Afr[i][2], b1a, a);
            acc[i] = mfma(Afr[i][3], b1b, a);
        }
        const f32x4 sA01 = (dsel & 1) ? acc[1] : acc[0];
        const f32x4 sA23 = (dsel & 1) ? acc[3] : acc[2];
        const f32x4 gA = (dsel & 2) ? sA23 : sA01;
        const f32x4 sB01 = (dsel & 1) ? acc[5] : acc[4];
        const f32x4 sB23 = (dsel & 1) ? acc[7] : acc[6];
        const f32x4 gB = (dsel & 2) ? sB23 : sB01;
        {
            const float gi = sigm_s(gA[0]);
            const float gf = sigm_s(gA[1]);
            const float zz = tanh_s(gA[2]);
            const float go = sigm_s(gA[3]);
            const float cn = gf * cst1 + gi * zz;
            s_hf[u1][cb] = go * tanh_n(cn);
        }
        {
            const float gi = sigm_s(gB[0]);
            const float gf = sigm_s(gB[1]);
            const float zz = tanh_s(gB[2]);
            const float go = sigm_s(gB[3]);
            const float cn = gf * cst2 + gi * zz;
            s_hf[u1 + 16][cb] = go * tanh_n(cn);
        }
    }
    __syncthreads();

    // ---- FC epilogue (4 batches, 256 threads) ----
    for (int i2 = tid; i2 < 32 * 64; i2 += 256) {
        const int m = i2 >> 6, uu = i2 & 63;
        s_fcw[m * 65 + uu] = fc1w[i2];
    }
    __syncthreads();
    if (tid < 128) {
        const int m = tid >> 2, jj = tid & 3;
        float acc = fc1b[m];
#pragma unroll
        for (int uu = 0; uu < Hh; ++uu)
            acc = fmaf(s_fcw[m * 65 + uu], s_hf[uu][jj], acc);
        s_fc[m][jj] = fmaxf(acc, 0.f);
    }
    __syncthreads();
    if (tid < 4) {
        float acc = fc2b[0];
#pragma unroll
        for (int m = 0; m < 32; ++m)
            acc = fmaf(fc2w[m], s_fc[m][tid], acc);
        out[b0 + tid] = acc;
    }
}

}  // namespace

extern "C" void kernel_launch(void* const* d_in, const int* in_sizes, int n_in,
                              void* d_out, int out_size, void* d_ws, size_t ws_size,
                              hipStream_t stream) {
    const float* x    = (const float*)d_in[0];
    const float* Wih0 = (const float*)d_in[1];
    const float* Whh0 = (const float*)d_in[2];
    const float* bih0 = (const float*)d_in[3];
    const float* bhh0 = (const float*)d_in[4];
    const float* Wih1 = (const float*)d_in[5];
    const float* Whh1 = (const float*)d_in[6];
    const float* bih1 = (const float*)d_in[7];
    const float* bhh1 = (const float*)d_in[8];
    const float* fc1w = (const float*)d_in[9];
    const float* fc1b = (const float*)d_in[10];
    const float* fc2w = (const float*)d_in[11];
    const float* fc2b = (const float*)d_in[12];
    float* out = (float*)d_out;

    lstm_f16<<<dim3(256), dim3(256), 0, stream>>>(
        x, Wih0, Whh0, bih0, bhh0, Wih1, Whh1, bih1, bhh1,
        fc1w, fc1b, fc2w, fc2b, out);
}

// Round 15
// 271.614 us; speedup vs baseline: 1.3197x; 1.3197x over previous
//
#include <hip/hip_runtime.h>
#include <math.h>
#include <stdint.h>

// LSTMModel B=1024 T=512 D=32 H=64, 2 layers + fc1(relu) + fc2.
// FINAL (= Round 10, best measured: 271.9 us): 256 blocks x 4 batches,
// layer-split waves (w0-3 = L0, w4-7 = L1, 4 tiles each), per-step
// s_barrier replaced by LDS flag synchronization:
//   - h0/h1 live in depth-6 slot rings; h(t) -> slot (t+1)%6.
//   - monotone counters s_cnt0/s_cnt1[slot]: +=1 per producing wave;
//     h(t) ready <=> cnt[(t+1)%6] >= 4*((t+1)/6 + 1). Slot 0 pre-marked
//     ready (h(-1) = 0).
//   - s_cons counts L1 h0-consumptions; L0 writing h0(t) (slot reuse
//     distance 6) requires s_cons >= 4*(t-4).
// Weights register-resident as fp16 MFMA A-fragments (log2e folded),
// bias as MFMA C-init, x per-lane direct from global (depth-2 prefetch),
// in-register cell update via acc-row permutation, dup-free h frags with
// wrap-read (4-lane broadcast).
//
// Structural-floor note (R7-R14 sweep): wall = 512 x step-interval;
// interval bracketed 1275-1810 cyc across barrier/loose-flag/tight-flag/
// 4-wave structures; dependency floor ~480 cyc; the excess is LDS-pipe
// serialization + barrier skew + issue contention. TLP via co-resident
// blocks requires VGPR <= 64/128 (weights need >= 112/wave -> spill,
// measured R6/R8); in-wave feedback needs 16 tiles = 256 VGPR A-frags;
// LDS-resident weights cost >= 1000 cyc/step of LDS bandwidth. Hence
// ~272 us is the practical floor of this decomposition on MI355X.

namespace {

constexpr int Hh = 64, Dd = 32, Tt = 512, DEP = 6;
constexpr float LOG2E = 1.4426950408889634f;

typedef _Float16 f16x8 __attribute__((ext_vector_type(8)));
typedef float f32x4 __attribute__((ext_vector_type(4)));

__device__ __forceinline__ f32x4 mfma(f16x8 a, f16x8 b, f32x4 c) {
    return __builtin_amdgcn_mfma_f32_16x16x32_f16(a, b, c, 0, 0, 0);
}
__device__ __forceinline__ float rcpf(float x) { return __builtin_amdgcn_rcpf(x); }
__device__ __forceinline__ float exp2f_(float x) { return __builtin_amdgcn_exp2f(x); }
__device__ __forceinline__ float sigm_s(float p) { return rcpf(1.0f + exp2f_(-p)); }
__device__ __forceinline__ float tanh_s(float p) {
    return 1.0f - 2.0f * rcpf(exp2f_(p) + 1.0f);
}
__device__ __forceinline__ float tanh_n(float c) {
    return 1.0f - 2.0f * rcpf(exp2f_(c * (2.0f * LOG2E)) + 1.0f);
}
__device__ __forceinline__ f16x8 cvt8s(const float* p, float sc) {
    f16x8 r;
#pragma unroll
    for (int e = 0; e < 8; ++e) r[e] = (_Float16)(p[e] * sc);
    return r;
}
__device__ __forceinline__ int ld_acq(const int* p) {
    return __hip_atomic_load(p, __ATOMIC_ACQUIRE, __HIP_MEMORY_SCOPE_WORKGROUP);
}
__device__ __forceinline__ void add_rel(int* p, int v) {
    __hip_atomic_fetch_add(p, v, __ATOMIC_RELEASE, __HIP_MEMORY_SCOPE_WORKGROUP);
}

__global__ __launch_bounds__(512, 2) void lstm_f16(
    const float* __restrict__ x,     // [B, T, D]
    const float* __restrict__ Wih0,  // [256, 32]
    const float* __restrict__ Whh0,  // [256, 64]
    const float* __restrict__ bih0, const float* __restrict__ bhh0,
    const float* __restrict__ Wih1,  // [256, 64]
    const float* __restrict__ Whh1,  // [256, 64]
    const float* __restrict__ bih1, const float* __restrict__ bhh1,
    const float* __restrict__ fc1w,  // [32, 64]
    const float* __restrict__ fc1b,  // [32]
    const float* __restrict__ fc2w,  // [1, 32]
    const float* __restrict__ fc2b,  // [1]
    float* __restrict__ out)         // [B]
{
    // slot rings: [slot][kfrag][row = kq*4 + col][e]; 256 f16 per slot
    __shared__ __align__(16) _Float16 s_h0[DEP][2][16][8];  // 3 KB
    __shared__ __align__(16) _Float16 s_h1[DEP][2][16][8];  // 3 KB
    __shared__ int s_cnt0[DEP];
    __shared__ int s_cnt1[DEP];
    __shared__ int s_cons;
    __shared__ float s_hf[Hh][5];
    __shared__ float s_fcw[32 * 65];
    __shared__ float s_fc[32][5];

    const int tid = threadIdx.x;   // 0..511
    const int w = tid >> 6;        // wave 0..7
    const int l = tid & 63;
    const int ar = l & 15;         // A row within tile
    const int akb = l >> 4;        // k-group
    const int cq = l >> 4;         // C/D row block
    const int cj = l & 15;         // C/D col
    const int cb = cj & 3;         // real batch col
    const int dd = cj >> 2;        // tile select for update (0..3)
    const bool isL1w = (w >= 4);   // wave role
    const int wl = w & 3;
    const int b0 = blockIdx.x * 4;

    // ---- persistent A fragments (log2e folded), 4 tiles x 4 k-slots ----
    const int r4 = ar & 3;
    const float sc = (r4 == 2) ? 2.0f * LOG2E : LOG2E;
    const int grow = r4 * 64 + 16 * wl + 4 * (ar >> 2);
    f16x8 Afr[4][4];
    if (!isL1w) {
#pragma unroll
        for (int i = 0; i < 4; ++i) {
            const int g = grow + i;
            Afr[i][0] = cvt8s(Wih0 + g * Dd + akb * 8, sc);       // x
            Afr[i][1] = cvt8s(Whh0 + g * Hh + akb * 8, sc);       // h0 k0-31
            Afr[i][2] = cvt8s(Whh0 + g * Hh + 32 + akb * 8, sc);  // h0 k32-63
            Afr[i][3] = Afr[i][1];                                 // unused
        }
    } else {
#pragma unroll
        for (int i = 0; i < 4; ++i) {
            const int g = grow + i;
            Afr[i][0] = cvt8s(Wih1 + g * Hh + akb * 8, sc);       // h0 k0-31
            Afr[i][1] = cvt8s(Wih1 + g * Hh + 32 + akb * 8, sc);  // h0 k32-63
            Afr[i][2] = cvt8s(Whh1 + g * Hh + akb * 8, sc);       // h1 k0-31
            Afr[i][3] = cvt8s(Whh1 + g * Hh + 32 + akb * 8, sc);  // h1 k32-63
        }
    }

    // bias as MFMA C-init
    const float* bi = isL1w ? bih1 : bih0;
    const float* bhp = isL1w ? bhh1 : bhh0;
    f32x4 biasT[4];
#pragma unroll
    for (int i = 0; i < 4; ++i)
#pragma unroll
        for (int r = 0; r < 4; ++r) {
            const float s2 = (r == 2) ? 2.0f * LOG2E : LOG2E;
            const int uu = 16 * wl + 4 * cq + i;
            biasT[i][r] = s2 * (bi[r * 64 + uu] + bhp[r * 64 + uu]);
        }

    // lane's update target: unit ub (its layer), col cb
    const int ub = 16 * wl + 4 * cq + dd;
    const int kf_h = ub >> 5;
    const int row_h = ((ub & 31) >> 3) * 4 + cb;
    const int e_h = ub & 7;
    _Float16* const wb0 = &s_h0[0][kf_h][row_h][e_h];
    _Float16* const wb1 = &s_h1[0][kf_h][row_h][e_h];

    // b-frag read row: wrap col = l&3 (4-lane broadcast)
    const int rrow = (l >> 4) * 4 + (l & 3);
    const _Float16* const rb0 = &s_h0[0][0][rrow][0];
    const _Float16* const rb1 = &s_h1[0][0][rrow][0];

    // ---- init LDS ----
    {
        int* p0 = (int*)s_h0;
        int* p1 = (int*)s_h1;
        for (int i = tid; i < DEP * 128; i += 512) { p0[i] = 0; p1[i] = 0; }
        if (tid < DEP) {
            s_cnt0[tid] = (tid == 0) ? 4 : 0;
            s_cnt1[tid] = (tid == 0) ? 4 : 0;
        }
        if (tid == DEP) s_cons = 0;
    }
    __syncthreads();

    float lasth = 0.f;

    if (!isL1w) {
        // =================== layer-0 waves ===================
        const float* xbase = x + ((size_t)(b0 + cb) * Tt) * Dd + akb * 8;
        float4 xr0 = *(const float4*)(xbase);
        float4 xr1 = *(const float4*)(xbase + 4);
        f16x8 xcur;
#pragma unroll
        for (int e = 0; e < 4; ++e) {
            xcur[e] = (_Float16)xr0[e];
            xcur[4 + e] = (_Float16)xr1[e];
        }
        xr0 = *(const float4*)(xbase + Dd);
        xr1 = *(const float4*)(xbase + Dd + 4);

        float cst = 0.f;
        int rs = 0, tgt = 4;
        for (int t = 0; t < Tt; ++t) {
            // wait h0(t-1) ready
            while (ld_acq(&s_cnt0[rs]) < tgt) __builtin_amdgcn_s_sleep(1);
            const f16x8 b0a = *(const f16x8*)(rb0 + rs * 256);
            const f16x8 b0b = *(const f16x8*)(rb0 + rs * 256 + 128);

            f32x4 acc[4];
#pragma unroll
            for (int i = 0; i < 4; ++i) {
                f32x4 a = mfma(Afr[i][0], xcur, biasT[i]);
                a = mfma(Afr[i][1], b0a, a);
                a = mfma(Afr[i][2], b0b, a);
                acc[i] = a;
            }
            // rotate x prefetch (depth 2)
            f16x8 xn;
#pragma unroll
            for (int e = 0; e < 4; ++e) {
                xn[e] = (_Float16)xr0[e];
                xn[4 + e] = (_Float16)xr1[e];
            }
            const int tf = (t + 2 < Tt) ? (t + 2) : (Tt - 1);
            xr0 = *(const float4*)(xbase + (size_t)tf * Dd);
            xr1 = *(const float4*)(xbase + (size_t)tf * Dd + 4);
            xcur = xn;

            const f32x4 g01 = (dd & 1) ? acc[1] : acc[0];
            const f32x4 g23 = (dd & 1) ? acc[3] : acc[2];
            const f32x4 gg = (dd & 2) ? g23 : g01;
            const float gi = sigm_s(gg[0]);
            const float gf = sigm_s(gg[1]);
            const float zz = tanh_s(gg[2]);
            const float go = sigm_s(gg[3]);
            cst = gf * cst + gi * zz;
            const float hv = go * tanh_n(cst);

            const int ws = (rs + 1 == DEP) ? 0 : rs + 1;
            // backpressure: slot ws holds h0(t-6); L1 must have consumed it
            if (t >= DEP - 1)
                while (ld_acq(&s_cons) < 4 * (t - 4)) __builtin_amdgcn_s_sleep(1);
            wb0[ws * 256] = (_Float16)hv;
            if (l == 0) add_rel(&s_cnt0[ws], 1);
            rs = ws;
            if (rs == 0) tgt += 4;
        }
    } else {
        // =================== layer-1 waves ===================
        float cst = 0.f;
        int rs0 = 1, t0 = 4;   // h0(s) slot/target
        int rs1 = 0, t1 = 4;   // h1(s-1) slot/target
        for (int s = 0; s < Tt; ++s) {
            while (ld_acq(&s_cnt0[rs0]) < t0) __builtin_amdgcn_s_sleep(1);
            while (ld_acq(&s_cnt1[rs1]) < t1) __builtin_amdgcn_s_sleep(1);
            const f16x8 b0a = *(const f16x8*)(rb0 + rs0 * 256);
            const f16x8 b0b = *(const f16x8*)(rb0 + rs0 * 256 + 128);
            const f16x8 b1a = *(const f16x8*)(rb1 + rs1 * 256);
            const f16x8 b1b = *(const f16x8*)(rb1 + rs1 * 256 + 128);

            f32x4 acc[4];
#pragma unroll
            for (int i = 0; i < 4; ++i) {
                f32x4 a = mfma(Afr[i][0], b0a, biasT[i]);
                a = mfma(Afr[i][1], b0b, a);
                a = mfma(Afr[i][2], b1a, a);
                a = mfma(Afr[i][3], b1b, a);
                acc[i] = a;
            }
            const f32x4 g01 = (dd & 1) ? acc[1] : acc[0];
            const f32x4 g23 = (dd & 1) ? acc[3] : acc[2];
            const f32x4 gg = (dd & 2) ? g23 : g01;
            const float gi = sigm_s(gg[0]);
            const float gf = sigm_s(gg[1]);
            const float zz = tanh_s(gg[2]);
            const float go = sigm_s(gg[3]);
            cst = gf * cst + gi * zz;
            const float hv = go * tanh_n(cst);
            lasth = hv;

            wb1[rs0 * 256] = (_Float16)hv;   // h1(s) -> slot (s+1)%DEP
            if (l == 0) {
                add_rel(&s_cnt1[rs0], 1);
                add_rel(&s_cons, 1);
            }
            rs1 = rs0;
            t1 = t0;
            rs0 = (rs0 + 1 == DEP) ? 0 : rs0 + 1;
            if (rs0 == 0) t0 += 4;
        }
        s_hf[ub][cb] = lasth;  // h1(511)
    }
    __syncthreads();

    // ---- FC epilogue (4 batches) ----
    for (int i2 = tid; i2 < 32 * 64; i2 += 512) {
        const int m = i2 >> 6, uu = i2 & 63;
        s_fcw[m * 65 + uu] = fc1w[i2];
    }
    __syncthreads();
    if (tid < 128) {
        const int m = tid >> 2, jj = tid & 3;
        float acc = fc1b[m];
#pragma unroll
        for (int uu = 0; uu < Hh; ++uu)
            acc = fmaf(s_fcw[m * 65 + uu], s_hf[uu][jj], acc);
        s_fc[m][jj] = fmaxf(acc, 0.f);
    }
    __syncthreads();
    if (tid < 4) {
        float acc = fc2b[0];
#pragma unroll
        for (int m = 0; m < 32; ++m)
            acc = fmaf(fc2w[m], s_fc[m][tid], acc);
        out[b0 + tid] = acc;
    }
}

}  // namespace

extern "C" void kernel_launch(void* const* d_in, const int* in_sizes, int n_in,
                              void* d_out, int out_size, void* d_ws, size_t ws_size,
                              hipStream_t stream) {
    const float* x    = (const float*)d_in[0];
    const float* Wih0 = (const float*)d_in[1];
    const float* Whh0 = (const float*)d_in[2];
    const float* bih0 = (const float*)d_in[3];
    const float* bhh0 = (const float*)d_in[4];
    const float* Wih1 = (const float*)d_in[5];
    const float* Whh1 = (const float*)d_in[6];
    const float* bih1 = (const float*)d_in[7];
    const float* bhh1 = (const float*)d_in[8];
    const float* fc1w = (const float*)d_in[9];
    const float* fc1b = (const float*)d_in[10];
    const float* fc2w = (const float*)d_in[11];
    const float* fc2b = (const float*)d_in[12];
    float* out = (float*)d_out;

    lstm_f16<<<dim3(256), dim3(512), 0, stream>>>(
        x, Wih0, Whh0, bih0, bhh0, Wih1, Whh1, bih1, bhh1,
        fc1w, fc1b, fc2w, fc2b, out);
}